// Round 3
// baseline (607.495 us; speedup 1.0000x reference)
//
#include <hip/hip_runtime.h>
#include <hip/hip_cooperative_groups.h>
#include <math.h>

// Problem constants (fixed by reference)
#define B_ 8
#define N_ 384
#define D_ 256
#define H_ 1024

#define NBLK 384          // cooperative grid: 1.5 blocks/CU, co-residency capacity is 2/CU
#define NTHR 512          // 8 waves
#define LDB 72            // LDS row stride in bf16 (64 data + 8 pad)
#define SMEM_BYTES 36864  // max over stages: gemm1 36864, gemm2 27648, dist 34048

namespace cg = cooperative_groups;

typedef __bf16 bh;
typedef __bf16 bf16x8 __attribute__((ext_vector_type(8)));
typedef __bf16 bf16x4 __attribute__((ext_vector_type(4)));
typedef float  f32x4  __attribute__((ext_vector_type(4)));
typedef _Float16 h2 __attribute__((ext_vector_type(2)));

#if __has_builtin(__builtin_amdgcn_fdot2)
#define FDOT2(a,b,c) __builtin_amdgcn_fdot2((a),(b),(c),false)
#else
#define FDOT2(a,b,c) ((c) + (float)(a).x*(float)(b).x + (float)(a).y*(float)(b).y)
#endif

__device__ inline h2 habs2(h2 x) {
    unsigned u = __builtin_bit_cast(unsigned, x) & 0x7fff7fffu;
    return __builtin_bit_cast(h2, u);
}

// split fp32 -> hi + lo bf16 (3xbf16 trick: a*b ~= ah*bh + ah*bl + al*bh, rel err ~2^-16)
__device__ inline void split2(float v, bh& h, bh& l) {
    h = (bh)v;
    l = (bh)(v - (float)h);
}

// box_num is logically int64; harness may hand int32. box_num >= 1 always, so
// int64-LE layout has all odd words zero -> runtime-detectable.
__device__ inline int load_boxnum(const int* __restrict__ p, int b) {
    bool is64 = ((p[1] | p[3] | p[5] | p[7]) == 0);
    return is64 ? p[2 * b] : p[b];
}

struct P {
    const float* x;
    const float* adj;
    const int*   box;
    const float* fc1w;
    const float* fc1b;
    const float* fc2w;
    const float* fc2b;
    const float* lw;
    float* soft;          // (B,N,N) output
    float* xhat;          // (B*N,D) output
    bh *w1h, *w1l, *w2h, *w2l;   // pre-split weights
    bh *xh, *xl;                 // pre-split x
    bh *c1h, *c1l;               // hidden activations hi/lo
    _Float16* x16;               // fp16 xhat for dist
};

// ---------------- stage 0: split x/w1/w2 to hi/lo bf16, zero soft_adj ----------------
__device__ void s_split(const P& p) {
    const int gsz = NBLK * NTHR;  // 196608
    const int gt = blockIdx.x * NTHR + threadIdx.x;
    // zero soft_adj (atomicAdd target): 8*384*384 floats = 294912 float4
    for (int i = gt; i < (B_ * N_ * N_) / 4; i += gsz)
        ((float4*)p.soft)[i] = float4{0.f, 0.f, 0.f, 0.f};
    // splits (in float4 quads): x 196608, w1 65536, w2 65536
    const int nx = (B_ * N_ * D_) / 4, nw = (H_ * D_) / 4;
    for (int qd = gt; qd < nx + 2 * nw; qd += gsz) {
        const float* s; bh* ph; bh* pl; int i;
        if (qd < nx)           { s = p.x;    ph = p.xh;  pl = p.xl;  i = qd; }
        else if (qd < nx + nw) { s = p.fc1w; ph = p.w1h; pl = p.w1l; i = qd - nx; }
        else                   { s = p.fc2w; ph = p.w2h; pl = p.w2l; i = qd - nx - nw; }
        float4 v = ((const float4*)s)[i];
        bf16x4 hv, lv; bh hh, ll;
        split2(v.x, hh, ll); hv[0] = hh; lv[0] = ll;
        split2(v.y, hh, ll); hv[1] = hh; lv[1] = ll;
        split2(v.z, hh, ll); hv[2] = hh; lv[2] = ll;
        split2(v.w, hh, ll); hv[3] = hh; lv[3] = ll;
        *(bf16x4*)(ph + 4 * (size_t)i) = hv;
        *(bf16x4*)(pl + 4 * (size_t)i) = lv;
    }
}

// ---------------- stage 1: gemm1 c1 = relu(x @ fc1_w^T + b1), 64x64 tiles, 8 waves ----------------
// 768 tiles -> exactly 2 grid-stride rounds on 384 blocks.
__device__ void s_gemm1(const P& p, char* sm) {
    bh* AhS = (bh*)sm;                 // 64*LDB each
    bh* AlS = AhS + 64 * LDB;
    bh* WhS = AlS + 64 * LDB;
    bh* WlS = WhS + 64 * LDB;
    const int tid = threadIdx.x;
    const int r = tid >> 3, kq = (tid & 7) * 8;       // staging: 64 rows x 64 k
    const int lane = tid & 63, wv = tid >> 6;
    const int wm = (wv & 1) * 32, wn = (wv >> 1) * 16;  // wave tile 32x16
    const int l15 = lane & 15, q = lane >> 4;

    for (int t = blockIdx.x; t < 768; t += NBLK) {
        const int n0 = (t & 15) * 64, m0 = (t >> 4) * 64;
        f32x4 acc[2] = {};
        for (int k0 = 0; k0 < D_; k0 += 64) {
            bf16x8 ah = *(const bf16x8*)(p.xh  + (size_t)(m0 + r) * D_ + k0 + kq);
            bf16x8 al = *(const bf16x8*)(p.xl  + (size_t)(m0 + r) * D_ + k0 + kq);
            bf16x8 wh = *(const bf16x8*)(p.w1h + (size_t)(n0 + r) * D_ + k0 + kq);
            bf16x8 wl = *(const bf16x8*)(p.w1l + (size_t)(n0 + r) * D_ + k0 + kq);
            __syncthreads();
            *(bf16x8*)&AhS[r * LDB + kq] = ah;
            *(bf16x8*)&AlS[r * LDB + kq] = al;
            *(bf16x8*)&WhS[r * LDB + kq] = wh;
            *(bf16x8*)&WlS[r * LDB + kq] = wl;
            __syncthreads();
            #pragma unroll
            for (int ks = 0; ks < 2; ks++) {
                const int kb = ks * 32 + q * 8;
                bf16x8 fah[2], fal[2];
                #pragma unroll
                for (int mi = 0; mi < 2; mi++) {
                    int row = wm + mi * 16 + l15;
                    fah[mi] = *(const bf16x8*)&AhS[row * LDB + kb];
                    fal[mi] = *(const bf16x8*)&AlS[row * LDB + kb];
                }
                bf16x8 fwh = *(const bf16x8*)&WhS[(wn + l15) * LDB + kb];
                bf16x8 fwl = *(const bf16x8*)&WlS[(wn + l15) * LDB + kb];
                #pragma unroll
                for (int mi = 0; mi < 2; mi++) {
                    acc[mi] = __builtin_amdgcn_mfma_f32_16x16x32_bf16(fah[mi], fwh, acc[mi], 0, 0, 0);
                    acc[mi] = __builtin_amdgcn_mfma_f32_16x16x32_bf16(fah[mi], fwl, acc[mi], 0, 0, 0);
                    acc[mi] = __builtin_amdgcn_mfma_f32_16x16x32_bf16(fal[mi], fwh, acc[mi], 0, 0, 0);
                }
            }
        }
        const int col = n0 + wn + l15;
        const float bb = p.fc1b[col];
        #pragma unroll
        for (int mi = 0; mi < 2; mi++)
            #pragma unroll
            for (int reg = 0; reg < 4; reg++) {
                int row = m0 + wm + mi * 16 + q * 4 + reg;
                float v = fmaxf(acc[mi][reg] + bb, 0.f);
                bh h, l; split2(v, h, l);
                size_t off = (size_t)row * H_ + col;
                p.c1h[off] = h; p.c1l[off] = l;
            }
    }
}

// ---------------- stage 2: gemm2 xhat = c1 @ fc2_w^T + b2, 64x32 tiles, 8 waves ----------------
// 384 tiles -> exactly 1 round. Writes fp32 xhat + fp16 copy for dist.
__device__ void s_gemm2(const P& p, char* sm) {
    bh* AhS = (bh*)sm;                 // 64*LDB
    bh* AlS = AhS + 64 * LDB;
    bh* WhS = AlS + 64 * LDB;          // 32*LDB
    bh* WlS = WhS + 32 * LDB;
    const int tid = threadIdx.x;
    const int t = blockIdx.x;          // 384 tiles exactly
    const int n0 = (t & 7) * 32, m0 = (t >> 3) * 64;
    const int lane = tid & 63, wv = tid >> 6;
    const int wm = (wv & 3) * 16, wn = (wv >> 2) * 16;  // wave tile 16x16
    const int l15 = lane & 15, q = lane >> 4;
    const int r = tid >> 3, kq = (tid & 7) * 8;         // A staging: 64 rows x 64 k
    const int t2 = tid & 255;
    const int rw = t2 >> 3, kw = (t2 & 7) * 8;          // W staging: 32 rows x 64 k, hi(0-255)/lo(256-511)

    f32x4 acc = {};
    for (int k0 = 0; k0 < H_; k0 += 64) {
        bf16x8 ah = *(const bf16x8*)(p.c1h + (size_t)(m0 + r) * H_ + k0 + kq);
        bf16x8 al = *(const bf16x8*)(p.c1l + (size_t)(m0 + r) * H_ + k0 + kq);
        const bh* wsrc = (tid < 256) ? p.w2h : p.w2l;
        bf16x8 wv8 = *(const bf16x8*)(wsrc + (size_t)(n0 + rw) * H_ + k0 + kw);
        __syncthreads();
        *(bf16x8*)&AhS[r * LDB + kq] = ah;
        *(bf16x8*)&AlS[r * LDB + kq] = al;
        bh* wdst = (tid < 256) ? WhS : WlS;
        *(bf16x8*)&wdst[rw * LDB + kw] = wv8;
        __syncthreads();
        #pragma unroll
        for (int ks = 0; ks < 2; ks++) {
            const int kb = ks * 32 + q * 8;
            bf16x8 fah = *(const bf16x8*)&AhS[(wm + l15) * LDB + kb];
            bf16x8 fal = *(const bf16x8*)&AlS[(wm + l15) * LDB + kb];
            bf16x8 fwh = *(const bf16x8*)&WhS[(wn + l15) * LDB + kb];
            bf16x8 fwl = *(const bf16x8*)&WlS[(wn + l15) * LDB + kb];
            acc = __builtin_amdgcn_mfma_f32_16x16x32_bf16(fah, fwh, acc, 0, 0, 0);
            acc = __builtin_amdgcn_mfma_f32_16x16x32_bf16(fah, fwl, acc, 0, 0, 0);
            acc = __builtin_amdgcn_mfma_f32_16x16x32_bf16(fal, fwh, acc, 0, 0, 0);
        }
    }
    const int col = n0 + wn + l15;
    const float bb = p.fc2b[col];
    #pragma unroll
    for (int reg = 0; reg < 4; reg++) {
        int row = m0 + wm + q * 4 + reg;
        float v = acc[reg] + bb;
        p.xhat[(size_t)row * D_ + col] = v;
        p.x16 [(size_t)row * D_ + col] = (_Float16)v;
    }
}

// ---------------- stage 3: dist partial sums (upper-triangle pairs x 2 k-halves) ----------------
// 336 units on 384 blocks. Raw weighted-L1 accumulated into soft via atomicAdd
// (2 fp32 addends, commutative -> deterministic). Mask+leaky deferred to stage 4.
#define DLX 132
__device__ void s_dist(const P& p, char* sm) {
    const int u = blockIdx.x;
    if (u >= 336) return;              // whole block skips (uniform); rejoins at grid.sync
    unsigned* X   = (unsigned*)sm;             // [64 k2][132 row-slots] = 33792 B
    unsigned* WkS = (unsigned*)(sm + 64 * DLX * 4);  // 64 words
    const int pair = u >> 1, kh = u & 1;
    const int b = pair / 21;
    int pp = pair % 21;
    int ti = 0;
    while (pp >= 6 - ti) { pp -= 6 - ti; ti++; }
    const int tj = ti + pp;
    const int i0 = ti * 64, j0 = tj * 64;
    const int tid = threadIdx.x;

    if (tid < 64) {
        float2 wp = ((const float2*)p.lw)[kh * 64 + tid];
        h2 wv = {(_Float16)wp.x, (_Float16)wp.y};
        WkS[tid] = __builtin_bit_cast(unsigned, wv);
    }
    // stage 128 rows x 128 dims (this k-half) fp16, k2-major
    const int sr = tid >> 2, cq = tid & 3;
    const int grow = (sr < 64) ? (i0 + sr) : (j0 + sr - 64);
    const _Float16* src = p.x16 + ((size_t)b * N_ + grow) * D_ + kh * 128 + cq * 32;
    #pragma unroll
    for (int ld = 0; ld < 4; ld++) {
        uint4 v = ((const uint4*)src)[ld];
        int k2 = cq * 16 + ld * 4;
        X[(k2 + 0) * DLX + sr] = v.x;
        X[(k2 + 1) * DLX + sr] = v.y;
        X[(k2 + 2) * DLX + sr] = v.z;
        X[(k2 + 3) * DLX + sr] = v.w;
    }
    __syncthreads();

    const int tx = tid & 31, ty = tid >> 5;   // 16x32 grid, 4x2 micro over 64x64
    float acc[4][2] = {};
    #pragma unroll 4
    for (int k2 = 0; k2 < 64; k2++) {
        uint4 av = *(const uint4*)&X[k2 * DLX + ty * 4];
        uint2 bv = *(const uint2*)&X[k2 * DLX + 64 + tx * 2];
        h2 wk = __builtin_bit_cast(h2, WkS[k2]);
        h2 ai[4] = {__builtin_bit_cast(h2, av.x), __builtin_bit_cast(h2, av.y),
                    __builtin_bit_cast(h2, av.z), __builtin_bit_cast(h2, av.w)};
        h2 bj[2] = {__builtin_bit_cast(h2, bv.x), __builtin_bit_cast(h2, bv.y)};
        #pragma unroll
        for (int ii = 0; ii < 4; ii++)
            #pragma unroll
            for (int jj = 0; jj < 2; jj++) {
                h2 d = habs2(ai[ii] - bj[jj]);
                acc[ii][jj] = FDOT2(d, wk, acc[ii][jj]);
            }
    }

    float* base = p.soft + (size_t)b * N_ * N_;
    #pragma unroll
    for (int ii = 0; ii < 4; ii++) {
        float* rp = base + (size_t)(i0 + ty * 4 + ii) * N_ + j0 + tx * 2;
        atomicAdd(rp,     acc[ii][0]);
        atomicAdd(rp + 1, acc[ii][1]);
    }
    if (ti != tj) {   // diagonal tiles: mirror would double-count under atomics
        #pragma unroll
        for (int jj = 0; jj < 2; jj++) {
            float* rp = base + (size_t)(j0 + tx * 2 + jj) * N_ + i0 + ty * 4;
            atomicAdd(rp,     acc[0][jj]);
            atomicAdd(rp + 1, acc[1][jj]);
            atomicAdd(rp + 2, acc[2][jj]);
            atomicAdd(rp + 3, acc[3][jj]);
        }
    }
}

// ---------------- stage 4: mask + leaky + row softmax; 8 rows/block -> 1 round ----------------
__device__ void s_softmax(const P& p) {
    const int wv = threadIdx.x >> 6, t = threadIdx.x & 63;
    const int row = blockIdx.x * 8 + wv;          // 384*8 = 3072 exactly
    const int b = row / N_, i = row - b * N_;
    float sumw = p.lw[t] + p.lw[t + 64] + p.lw[t + 128] + p.lw[t + 192];
    #pragma unroll
    for (int off = 32; off > 0; off >>= 1) sumw += __shfl_xor(sumw, off);
    const int bn = load_boxnum(p.box, b);
    const bool vi = i < bn;
    float* prow = p.soft + (size_t)row * N_;
    const float* arow = p.adj + (size_t)row * N_;
    float v[6];
    float m = -1e30f;
    #pragma unroll
    for (int qq = 0; qq < 6; qq++) {
        int j = t + qq * 64;
        float raw = prow[j];
        if (!(vi && (j < bn))) raw -= sumw;
        raw = raw > 0.f ? raw : 0.01f * raw;      // leaky
        v[qq] = raw;
        m = fmaxf(m, raw);
    }
    #pragma unroll
    for (int off = 32; off > 0; off >>= 1) m = fmaxf(m, __shfl_xor(m, off));
    float e[6];
    float s = 0.f;
    #pragma unroll
    for (int qq = 0; qq < 6; qq++) { e[qq] = arow[t + qq * 64] * expf(v[qq] - m); s += e[qq]; }
    #pragma unroll
    for (int off = 32; off > 0; off >>= 1) s += __shfl_xor(s, off);
    float inv = 1.0f / s;
    #pragma unroll
    for (int qq = 0; qq < 6; qq++) prow[t + qq * 64] = e[qq] * inv + 1e-10f;
}

// ---------------- cooperative mega-kernel: 1 launch, 4 grid syncs ----------------
__global__ __launch_bounds__(NTHR, 4) void mega(P p) {
    __shared__ __align__(16) char sm[SMEM_BYTES];
    cg::grid_group g = cg::this_grid();
    s_split(p);
    __threadfence(); g.sync();
    s_gemm1(p, sm);
    __threadfence(); g.sync();
    s_gemm2(p, sm);
    __threadfence(); g.sync();
    s_dist(p, sm);
    __threadfence(); g.sync();
    s_softmax(p);
}

// Fallback: same stages as 5 plain launches (used only if cooperative launch fails)
__global__ __launch_bounds__(NTHR, 4) void k_split(P p)   { s_split(p); }
__global__ __launch_bounds__(NTHR, 4) void k_gemm1(P p)   { __shared__ __align__(16) char sm[SMEM_BYTES]; s_gemm1(p, sm); }
__global__ __launch_bounds__(NTHR, 4) void k_gemm2(P p)   { __shared__ __align__(16) char sm[SMEM_BYTES]; s_gemm2(p, sm); }
__global__ __launch_bounds__(NTHR, 4) void k_dist(P p)    { __shared__ __align__(16) char sm[SMEM_BYTES]; s_dist(p, sm); }
__global__ __launch_bounds__(NTHR, 4) void k_softmax(P p) { s_softmax(p); }

extern "C" void kernel_launch(void* const* d_in, const int* in_sizes, int n_in,
                              void* d_out, int out_size, void* d_ws, size_t ws_size,
                              hipStream_t stream) {
    P p;
    p.x    = (const float*)d_in[0];
    p.adj  = (const float*)d_in[1];
    p.box  = (const int*)d_in[2];
    p.fc1w = (const float*)d_in[3];
    p.fc1b = (const float*)d_in[4];
    p.fc2w = (const float*)d_in[5];
    p.fc2b = (const float*)d_in[6];
    p.lw   = (const float*)d_in[7];
    p.soft = (float*)d_out;
    p.xhat = (float*)d_out + (size_t)B_ * N_ * N_;

    const int BN = B_ * N_;  // 3072
    char* w = (char*)d_ws;   // total ~18.5 MB of 256 MiB
    p.w1h = (bh*)w;                w += (size_t)H_ * D_ * 2;
    p.w1l = (bh*)w;                w += (size_t)H_ * D_ * 2;
    p.w2h = (bh*)w;                w += (size_t)D_ * H_ * 2;
    p.w2l = (bh*)w;                w += (size_t)D_ * H_ * 2;
    p.xh  = (bh*)w;                w += (size_t)BN * D_ * 2;
    p.xl  = (bh*)w;                w += (size_t)BN * D_ * 2;
    p.c1h = (bh*)w;                w += (size_t)BN * H_ * 2;
    p.c1l = (bh*)w;                w += (size_t)BN * H_ * 2;
    p.x16 = (_Float16*)w;

    void* args[] = {&p};
    hipError_t e = hipLaunchCooperativeKernel((const void*)mega, dim3(NBLK), dim3(NTHR),
                                              args, 0, stream);
    if (e != hipSuccess) {
        // capture-safe fallback: identical stages as separate launches
        k_split  <<<NBLK, NTHR, 0, stream>>>(p);
        k_gemm1  <<<NBLK, NTHR, 0, stream>>>(p);
        k_gemm2  <<<NBLK, NTHR, 0, stream>>>(p);
        k_dist   <<<NBLK, NTHR, 0, stream>>>(p);
        k_softmax<<<NBLK, NTHR, 0, stream>>>(p);
    }
}

// Round 4
// 123.690 us; speedup vs baseline: 4.9114x; 4.9114x over previous
//
#include <hip/hip_runtime.h>
#include <math.h>

// Problem constants (fixed by reference)
#define B_ 8
#define N_ 384
#define D_ 256
#define H_ 1024

typedef __bf16 bh;
typedef __bf16 bf16x8 __attribute__((ext_vector_type(8)));
typedef float  f32x4  __attribute__((ext_vector_type(4)));
typedef _Float16 h2 __attribute__((ext_vector_type(2)));

#define LDB  72    // LDS row stride (bf16) for 64-wide K tiles: 144 B rows, <=2-way banks
#define LDK2 136   // LDS row stride (bf16) for 128-wide K tiles: 272 B rows, same bank pattern

#if __has_builtin(__builtin_amdgcn_fdot2)
#define FDOT2(a,b,c) __builtin_amdgcn_fdot2((a),(b),(c),false)
#else
#define FDOT2(a,b,c) ((c) + (float)(a).x*(float)(b).x + (float)(a).y*(float)(b).y)
#endif

__device__ inline h2 habs2(h2 x) {
    unsigned u = __builtin_bit_cast(unsigned, x) & 0x7fff7fffu;
    return __builtin_bit_cast(h2, u);
}

// split fp32 -> hi + lo bf16 (3xbf16 trick: a*b ~= ah*bh + ah*bl + al*bh, rel err ~2^-16)
__device__ inline void split2(float v, bh& h, bh& l) {
    h = (bh)v;
    l = (bh)(v - (float)h);
}

__device__ inline void split8(const float* f, bf16x8& h8, bf16x8& l8) {
    #pragma unroll
    for (int i = 0; i < 8; i++) { bh h, l; split2(f[i], h, l); h8[i] = h; l8[i] = l; }
}

// box_num is logically int64; harness may hand int32. box_num >= 1 always, so
// int64-LE layout has all odd words zero -> runtime-detectable.
__device__ inline int load_boxnum(const int* __restrict__ p, int b) {
    bool is64 = ((p[1] | p[3] | p[5] | p[7]) == 0);
    return is64 ? p[2 * b] : p[b];
}

// ---------------- GEMM1: c1 = relu(x @ fc1_w^T + fc1_b), 64x64 tiles, inline fp32->hi/lo split ----------------
__global__ __launch_bounds__(256) void gemm1_kernel(
        const float* __restrict__ A,     // (rows,256) fp32 x
        const float* __restrict__ W,     // (1024,256) fp32 fc1_w
        const float* __restrict__ bias,
        bh* __restrict__ Ch, bh* __restrict__ Cl)   // (rows,1024) hi/lo
{
    __shared__ __align__(16) bh AhS[64 * LDB], AlS[64 * LDB], WhS[64 * LDB], WlS[64 * LDB];  // 36.9 KB
    const int tid = threadIdx.x;
    const int m0 = blockIdx.y * 64, n0 = blockIdx.x * 64;
    const int r = tid >> 2, kq = (tid & 3) * 16;   // staging: 4 threads/row x 16 elems
    const int lane = tid & 63, wv_ = tid >> 6;
    const int wm = (wv_ & 1) * 32, wn = (wv_ >> 1) * 32;
    const int l15 = lane & 15, q = lane >> 4;

    f32x4 acc[2][2] = {};
    for (int k0 = 0; k0 < D_; k0 += 64) {
        const float* ap = A + (size_t)(m0 + r) * D_ + k0 + kq;
        const float* wp = W + (size_t)(n0 + r) * D_ + k0 + kq;
        float af[16], wf[16];
        #pragma unroll
        for (int u = 0; u < 4; u++) {
            *(float4*)&af[4 * u] = *(const float4*)(ap + 4 * u);
            *(float4*)&wf[4 * u] = *(const float4*)(wp + 4 * u);
        }
        bf16x8 ah0, ah1, al0, al1, wh0, wh1, wl0, wl1;
        split8(af,     ah0, al0); split8(af + 8, ah1, al1);
        split8(wf,     wh0, wl0); split8(wf + 8, wh1, wl1);
        __syncthreads();
        *(bf16x8*)&AhS[r * LDB + kq]     = ah0;  *(bf16x8*)&AhS[r * LDB + kq + 8] = ah1;
        *(bf16x8*)&AlS[r * LDB + kq]     = al0;  *(bf16x8*)&AlS[r * LDB + kq + 8] = al1;
        *(bf16x8*)&WhS[r * LDB + kq]     = wh0;  *(bf16x8*)&WhS[r * LDB + kq + 8] = wh1;
        *(bf16x8*)&WlS[r * LDB + kq]     = wl0;  *(bf16x8*)&WlS[r * LDB + kq + 8] = wl1;
        __syncthreads();
        #pragma unroll
        for (int ks = 0; ks < 2; ks++) {
            const int kb = ks * 32 + q * 8;
            bf16x8 fah[2], fal[2], fwh[2], fwl[2];
            #pragma unroll
            for (int mi = 0; mi < 2; mi++) {
                int row = wm + mi * 16 + l15;
                fah[mi] = *(const bf16x8*)&AhS[row * LDB + kb];
                fal[mi] = *(const bf16x8*)&AlS[row * LDB + kb];
            }
            #pragma unroll
            for (int ni = 0; ni < 2; ni++) {
                int row = wn + ni * 16 + l15;
                fwh[ni] = *(const bf16x8*)&WhS[row * LDB + kb];
                fwl[ni] = *(const bf16x8*)&WlS[row * LDB + kb];
            }
            #pragma unroll
            for (int mi = 0; mi < 2; mi++)
                #pragma unroll
                for (int ni = 0; ni < 2; ni++) {
                    acc[mi][ni] = __builtin_amdgcn_mfma_f32_16x16x32_bf16(fah[mi], fwh[ni], acc[mi][ni], 0, 0, 0);
                    acc[mi][ni] = __builtin_amdgcn_mfma_f32_16x16x32_bf16(fah[mi], fwl[ni], acc[mi][ni], 0, 0, 0);
                    acc[mi][ni] = __builtin_amdgcn_mfma_f32_16x16x32_bf16(fal[mi], fwh[ni], acc[mi][ni], 0, 0, 0);
                }
        }
    }
    #pragma unroll
    for (int ni = 0; ni < 2; ni++) {
        int col = n0 + wn + ni * 16 + l15;
        float bb = bias[col];
        #pragma unroll
        for (int mi = 0; mi < 2; mi++)
            #pragma unroll
            for (int reg = 0; reg < 4; reg++) {
                int row = m0 + wm + mi * 16 + q * 4 + reg;
                float v = fmaxf(acc[mi][ni][reg] + bb, 0.f);
                bh h, l; split2(v, h, l);
                size_t off = (size_t)row * H_ + col;
                Ch[off] = h; Cl[off] = l;
            }
    }
}

// ---------------- GEMM2: xhat = c1 @ fc2_w^T + fc2_b; 64x32 tiles; K-stage 128 (16 barriers) ----------------
__global__ __launch_bounds__(256) void gemm2_kernel(
        const bh* __restrict__ Ah_, const bh* __restrict__ Al_,  // (rows,1024) c1 hi/lo
        const float* __restrict__ W,     // (256,1024) fp32 fc2_w, split inline
        const float* __restrict__ bias,
        float* __restrict__ C, _Float16* __restrict__ C16)       // (rows,256)
{
    __shared__ __align__(16) bh AhS[64 * LDK2], AlS[64 * LDK2], WhS[32 * LDK2], WlS[32 * LDK2];  // 52.2 KB
    const int tid = threadIdx.x;
    const int m0 = blockIdx.y * 64, n0 = blockIdx.x * 32;
    const int lane = tid & 63, wv_ = tid >> 6;
    const int wm = wv_ * 16;                       // 4 waves x 16 rows, full 32 cols each
    const int l15 = lane & 15, q = lane >> 4;
    const int r = tid >> 2, kq = (tid & 3) * 32;   // A staging: 4 thr/row x 32 elems
    const int rw = tid >> 3, kw = (tid & 7) * 16;  // W staging: 8 thr/row x 16 elems

    f32x4 acc[2] = {};
    for (int k0 = 0; k0 < H_; k0 += 128) {
        const bh* pah = Ah_ + (size_t)(m0 + r) * H_ + k0 + kq;
        const bh* pal = Al_ + (size_t)(m0 + r) * H_ + k0 + kq;
        bf16x8 va[4], vl[4];
        #pragma unroll
        for (int u = 0; u < 4; u++) {
            va[u] = *(const bf16x8*)(pah + 8 * u);
            vl[u] = *(const bf16x8*)(pal + 8 * u);
        }
        const float* wp = W + (size_t)(n0 + rw) * H_ + k0 + kw;
        float wf[16];
        #pragma unroll
        for (int u = 0; u < 4; u++) *(float4*)&wf[4 * u] = *(const float4*)(wp + 4 * u);
        bf16x8 wh0, wh1, wl0, wl1;
        split8(wf,     wh0, wl0); split8(wf + 8, wh1, wl1);
        __syncthreads();
        #pragma unroll
        for (int u = 0; u < 4; u++) {
            *(bf16x8*)&AhS[r * LDK2 + kq + 8 * u] = va[u];
            *(bf16x8*)&AlS[r * LDK2 + kq + 8 * u] = vl[u];
        }
        *(bf16x8*)&WhS[rw * LDK2 + kw]     = wh0;  *(bf16x8*)&WhS[rw * LDK2 + kw + 8] = wh1;
        *(bf16x8*)&WlS[rw * LDK2 + kw]     = wl0;  *(bf16x8*)&WlS[rw * LDK2 + kw + 8] = wl1;
        __syncthreads();
        #pragma unroll
        for (int ks = 0; ks < 4; ks++) {
            const int kb = ks * 32 + q * 8;
            const int arow = wm + l15;
            bf16x8 fah = *(const bf16x8*)&AhS[arow * LDK2 + kb];
            bf16x8 fal = *(const bf16x8*)&AlS[arow * LDK2 + kb];
            #pragma unroll
            for (int ni = 0; ni < 2; ni++) {
                int row = ni * 16 + l15;
                bf16x8 fwh = *(const bf16x8*)&WhS[row * LDK2 + kb];
                bf16x8 fwl = *(const bf16x8*)&WlS[row * LDK2 + kb];
                acc[ni] = __builtin_amdgcn_mfma_f32_16x16x32_bf16(fah, fwh, acc[ni], 0, 0, 0);
                acc[ni] = __builtin_amdgcn_mfma_f32_16x16x32_bf16(fah, fwl, acc[ni], 0, 0, 0);
                acc[ni] = __builtin_amdgcn_mfma_f32_16x16x32_bf16(fal, fwh, acc[ni], 0, 0, 0);
            }
        }
    }
    #pragma unroll
    for (int ni = 0; ni < 2; ni++) {
        int col = n0 + ni * 16 + l15;
        float bb = bias[col];
        #pragma unroll
        for (int reg = 0; reg < 4; reg++) {
            int row = m0 + wm + q * 4 + reg;
            float v = acc[ni][reg] + bb;
            C[(size_t)row * D_ + col] = v;
            C16[(size_t)row * D_ + col] = (_Float16)v;
        }
    }
}

// ---------------- pairwise weighted L1 + mask + leaky (unchanged from R1) ----------------
// Upper-triangle 64x64 tiles (21/batch, 168 blocks), mirror-written.
// 512 threads. Whole D=256 staged ONCE as fp16 into k2-major LDS -> single barrier,
// then 128 barrier-free packed-fp16 iterations at 2 waves/SIMD.
#define DLX 132   // row-slot stride (128 rows + 4 pad); 528 B per k2 -> 16B-aligned, reads <=2-way banks
__global__ __launch_bounds__(512) void dist_kernel(const _Float16* __restrict__ xh16,
                                                   const float* __restrict__ w,
                                                   const int* __restrict__ box_num,
                                                   float* __restrict__ dist) {
    __shared__ __align__(16) unsigned X[128 * DLX];   // [k2][row: 0-63 = i-block, 64-127 = j-block]
    __shared__ unsigned WkS[128];
    const int bidx = blockIdx.x;
    const int b = bidx / 21;
    int p = bidx % 21;
    int ti = 0;
    while (p >= 6 - ti) { p -= 6 - ti; ti++; }
    const int tj = ti + p;
    const int i0 = ti * 64, j0 = tj * 64;
    const int tid = threadIdx.x;
    const int lane = tid & 63;

    // sum(learn_w) per wave
    float sumw = w[lane] + w[lane + 64] + w[lane + 128] + w[lane + 192];
    #pragma unroll
    for (int off = 32; off > 0; off >>= 1) sumw += __shfl_xor(sumw, off);

    // w pairs as fp16x2 in LDS
    if (tid < 128) {
        float2 wp = *(const float2*)&w[2 * tid];
        h2 wv = {(_Float16)wp.x, (_Float16)wp.y};
        WkS[tid] = __builtin_bit_cast(unsigned, wv);
    }

    // stage 128 rows x 256 dims fp16 (64 KB) transposed to k2-major
    const int sr = tid >> 2, koff = (tid & 3) * 64;
    const int grow = (sr < 64) ? (i0 + sr) : (j0 + sr - 64);
    const _Float16* src = xh16 + ((size_t)b * N_ + grow) * D_ + koff;
    #pragma unroll
    for (int ld = 0; ld < 8; ld++) {
        uint4 v = *(const uint4*)(src + ld * 8);
        int k2 = (koff >> 1) + ld * 4;
        X[(k2 + 0) * DLX + sr] = v.x;
        X[(k2 + 1) * DLX + sr] = v.y;
        X[(k2 + 2) * DLX + sr] = v.z;
        X[(k2 + 3) * DLX + sr] = v.w;
    }
    __syncthreads();   // the ONLY barrier

    const int tx = tid & 31, ty = tid >> 5;   // 16x32 thread grid, 4x2 micro
    float acc[4][2] = {};
    #pragma unroll 4
    for (int k2 = 0; k2 < 128; k2++) {
        uint4 av = *(const uint4*)&X[k2 * DLX + ty * 4];        // 4 i-rows (broadcast x32)
        uint2 bv = *(const uint2*)&X[k2 * DLX + 64 + tx * 2];   // 2 j-rows (2-way banks)
        h2 wv = __builtin_bit_cast(h2, WkS[k2]);
        h2 ai[4] = {__builtin_bit_cast(h2, av.x), __builtin_bit_cast(h2, av.y),
                    __builtin_bit_cast(h2, av.z), __builtin_bit_cast(h2, av.w)};
        h2 bj[2] = {__builtin_bit_cast(h2, bv.x), __builtin_bit_cast(h2, bv.y)};
        #pragma unroll
        for (int ii = 0; ii < 4; ii++)
            #pragma unroll
            for (int jj = 0; jj < 2; jj++) {
                h2 d = habs2(ai[ii] - bj[jj]);
                acc[ii][jj] = FDOT2(d, wv, acc[ii][jj]);
            }
    }

    const int bn = load_boxnum(box_num, b);
    float m[4][2];
    #pragma unroll
    for (int ii = 0; ii < 4; ii++) {
        int i = i0 + ty * 4 + ii;
        bool vi = i < bn;
        #pragma unroll
        for (int jj = 0; jj < 2; jj++) {
            int j = j0 + tx * 2 + jj;
            float v = acc[ii][jj];
            if (!(vi && (j < bn))) v -= sumw;
            m[ii][jj] = v > 0.f ? v : 0.01f * v;
        }
    }
    // primary tile: rows i, cols j (coalesced float2)
    #pragma unroll
    for (int ii = 0; ii < 4; ii++) {
        int i = i0 + ty * 4 + ii;
        float2 o = {m[ii][0], m[ii][1]};
        *(float2*)&dist[((size_t)b * N_ + i) * N_ + j0 + tx * 2] = o;
    }
    // mirror tile: rows j, cols i (diagonal tiles double-write identical bits - benign)
    #pragma unroll
    for (int jj = 0; jj < 2; jj++) {
        int j = j0 + tx * 2 + jj;
        float4 o = {m[0][jj], m[1][jj], m[2][jj], m[3][jj]};
        *(float4*)&dist[((size_t)b * N_ + j) * N_ + i0 + ty * 4] = o;
    }
}

// ---------------- row softmax: 4 waves per block, one row per wave (unchanged from R1) ----------------
__global__ __launch_bounds__(256) void softmax_kernel(float* __restrict__ sa,
                                                      const float* __restrict__ adj) {
    const int row = blockIdx.x * 4 + (threadIdx.x >> 6);
    const int t = threadIdx.x & 63;
    float* prow = sa + (size_t)row * N_;
    const float* arow = adj + (size_t)row * N_;
    float v[6];
    float m = -1e30f;
    #pragma unroll
    for (int qq = 0; qq < 6; qq++) { v[qq] = prow[t + qq * 64]; m = fmaxf(m, v[qq]); }
    #pragma unroll
    for (int off = 32; off > 0; off >>= 1) m = fmaxf(m, __shfl_xor(m, off));
    float e[6];
    float s = 0.f;
    #pragma unroll
    for (int qq = 0; qq < 6; qq++) { e[qq] = arow[t + qq * 64] * expf(v[qq] - m); s += e[qq]; }
    #pragma unroll
    for (int off = 32; off > 0; off >>= 1) s += __shfl_xor(s, off);
    float inv = 1.0f / s;
    #pragma unroll
    for (int qq = 0; qq < 6; qq++) prow[t + qq * 64] = e[qq] * inv + 1e-10f;
}

extern "C" void kernel_launch(void* const* d_in, const int* in_sizes, int n_in,
                              void* d_out, int out_size, void* d_ws, size_t ws_size,
                              hipStream_t stream) {
    const float* x       = (const float*)d_in[0];
    const float* adj     = (const float*)d_in[1];
    const int*   box_num = (const int*)d_in[2];
    const float* fc1_w   = (const float*)d_in[3];
    const float* fc1_b   = (const float*)d_in[4];
    const float* fc2_w   = (const float*)d_in[5];
    const float* fc2_b   = (const float*)d_in[6];
    const float* learn_w = (const float*)d_in[7];

    float* soft_adj = (float*)d_out;
    float* xhat     = (float*)d_out + (size_t)B_ * N_ * N_;

    const int BN = B_ * N_;  // 3072

    // ws layout: [x16 fp16 (1.5 MB)] [chunk: c1h|c1l (bf16)]
    _Float16* xh16 = (_Float16*)d_ws;
    bh* cbase = (bh*)(xh16 + (size_t)BN * D_);
    const size_t fixed_bytes = (size_t)BN * D_ * 2;
    const size_t per_row = (size_t)H_ * 2 * 2;   // c1 hi+lo bytes per row = 4096

    long long avail = (long long)ws_size - (long long)fixed_bytes;
    long long mr = (avail > 0) ? (avail / (long long)per_row) : 0;
    if (mr > BN) mr = BN;
    mr &= ~63LL;
    if (mr < 64) mr = 64;    // ws is 256 MiB in this harness; single-chunk path in practice
    const int max_rows = (int)mr;

    for (int m0 = 0; m0 < BN; m0 += max_rows) {
        int rows = BN - m0; if (rows > max_rows) rows = max_rows;
        bh* c1h = cbase;
        bh* c1l = c1h + (size_t)max_rows * H_;

        dim3 g1(H_ / 64, rows / 64);
        gemm1_kernel<<<g1, 256, 0, stream>>>(x + (size_t)m0 * D_, fc1_w, fc1_b, c1h, c1l);
        dim3 g2(D_ / 32, rows / 64);
        gemm2_kernel<<<g2, 256, 0, stream>>>(c1h, c1l, fc2_w, fc2_b,
                                             xhat + (size_t)m0 * D_, xh16 + (size_t)m0 * D_);
    }

    dist_kernel<<<B_ * 21, 512, 0, stream>>>(xh16, learn_w, box_num, soft_adj);

    softmax_kernel<<<BN / 4, 256, 0, stream>>>(soft_adj, adj);
}